// Round 1
// baseline (3585.286 us; speedup 1.0000x reference)
//
#include <hip/hip_runtime.h>
#include <cmath>

#define TTOK 4096
#define CDIM 1024
#define NE 8
#define MLPD 4096
#define BMR 64
#define PCAP (2*TTOK + NE*BMR)   // 8704 padded token-expert pairs max

// ---------- helpers ----------
__device__ __forceinline__ float bf2f(unsigned short h){
  return __uint_as_float(((unsigned int)h) << 16);
}
__device__ __forceinline__ unsigned short f2bf(float f){
  unsigned int u = __float_as_uint(f);
  u += 0x7FFFu + ((u >> 16) & 1u);   // RNE
  return (unsigned short)(u >> 16);
}
__device__ __forceinline__ float gelu_exact(float x){
  return 0.5f * x * (1.0f + erff(x * 0.70710678118654752f));
}

// ---------- init ----------
__global__ __launch_bounds__(256) void k_zero(float* out, int n, int* counts, float* loadsum){
  int i = blockIdx.x*256 + threadIdx.x;
  if (i < n) out[i] = 0.f;
  if (i < NE){ counts[i] = 0; loadsum[i] = 0.f; }
}

// M2[i][e] = sum_j te_w2[i][j] * gate_w[2C+j][e];  c2[e] = sum_j te_b2[j]*gate_w[2C+j][e]
__global__ __launch_bounds__(256) void k_m2(const float* __restrict__ te_w2,
    const float* __restrict__ te_b2, const float* __restrict__ gate_w,
    float* __restrict__ M2, float* __restrict__ c2){
  int idx = blockIdx.x*256 + threadIdx.x;
  if (idx < CDIM*NE){
    int i = idx >> 3, e = idx & 7;
    float s = 0.f;
    for (int j = 0; j < CDIM; j++)
      s += te_w2[(size_t)i*CDIM + j] * gate_w[(size_t)(2*CDIM + j)*NE + e];
    M2[idx] = s;
  } else if (idx < CDIM*NE + NE){
    int e = idx - CDIM*NE;
    float s = 0.f;
    for (int j = 0; j < CDIM; j++)
      s += te_b2[j] * gate_w[(size_t)(2*CDIM + j)*NE + e];
    c2[e] = s;
  }
}

// ---------- gating ----------
__global__ __launch_bounds__(256) void k_gate(const float* __restrict__ x,
    const float* __restrict__ p, const float* __restrict__ t,
    const float* __restrict__ te_w1, const float* __restrict__ te_b1,
    const float* __restrict__ gate_w, const float* __restrict__ M2,
    const float* __restrict__ c2,
    int* __restrict__ ti, float* __restrict__ tg,
    int* __restrict__ counts, float* __restrict__ loadsum){
  int tok = blockIdx.x, tid = threadIdx.x;
  float tv = t[tok];
  float acc[NE];
  #pragma unroll
  for (int e = 0; e < NE; e++) acc[e] = 0.f;
  for (int j = tid; j < CDIM; j += 256){
    float xv = x[(size_t)tok*CDIM + j];
    float pv = p[(size_t)tok*CDIM + j];
    float vv = gelu_exact(tv*te_w1[j] + te_b1[j]);
    const float* g0 = gate_w + (size_t)j*NE;
    const float* g1 = gate_w + (size_t)(CDIM + j)*NE;
    const float* m2 = M2 + (size_t)j*NE;
    #pragma unroll
    for (int e = 0; e < NE; e++) acc[e] += xv*g0[e] + pv*g1[e] + vv*m2[e];
  }
  __shared__ float red[256][NE];
  #pragma unroll
  for (int e = 0; e < NE; e++) red[tid][e] = acc[e];
  __syncthreads();
  for (int s = 128; s > 0; s >>= 1){
    if (tid < s){
      #pragma unroll
      for (int e = 0; e < NE; e++) red[tid][e] += red[tid+s][e];
    }
    __syncthreads();
  }
  if (tid == 0){
    float lg[NE];
    #pragma unroll
    for (int e = 0; e < NE; e++) lg[e] = red[0][e] + c2[e];
    int i1 = 0; float l1 = lg[0];
    #pragma unroll
    for (int e = 1; e < NE; e++) if (lg[e] > l1){ l1 = lg[e]; i1 = e; }
    int i2 = -1; float l2 = -3.4e38f;
    #pragma unroll
    for (int e = 0; e < NE; e++) if (e != i1 && lg[e] > l2){ l2 = lg[e]; i2 = e; }
    float ex  = expf(l2 - l1);        // softmax over top-2, max-subtracted
    float g1v = 1.f/(1.f + ex);
    float g2v = ex/(1.f + ex);
    ti[tok*2]   = i1; ti[tok*2+1] = i2;
    tg[tok*2]   = g1v; tg[tok*2+1] = g2v;
    atomicAdd(&counts[i1], 1);  atomicAdd(&counts[i2], 1);
    atomicAdd(&loadsum[i1], g1v); atomicAdd(&loadsum[i2], g2v);
  }
}

// ---------- dispatch ----------
__global__ __launch_bounds__(256) void k_scan(const int* __restrict__ counts,
    int* __restrict__ poff, int* __restrict__ fillpos,
    int* __restrict__ tok_id, float* __restrict__ pgate, int* __restrict__ pe){
  __shared__ int so[NE+1];
  __shared__ int sc[NE];
  if (threadIdx.x == 0){
    int o = 0;
    for (int e = 0; e < NE; e++){
      so[e] = o; poff[e] = o; fillpos[e] = o;
      sc[e] = counts[e];
      o += (sc[e] + BMR - 1) & ~(BMR - 1);   // pad each expert to 64-row tiles
    }
    so[NE] = o; poff[NE] = o;
  }
  __syncthreads();
  for (int e = 0; e < NE; e++){
    int s = so[e] + sc[e], en = so[e+1];
    for (int i = s + (int)threadIdx.x; i < en; i += 256){
      tok_id[i] = 0; pgate[i] = 0.f; pe[i] = e;   // dummy rows: gate 0
    }
  }
}

__global__ __launch_bounds__(256) void k_fill(const int* __restrict__ ti,
    const float* __restrict__ tg, int* __restrict__ fillpos,
    int* __restrict__ tok_id, float* __restrict__ pgate, int* __restrict__ pe){
  int tok = blockIdx.x*256 + threadIdx.x;
  if (tok >= TTOK) return;
  #pragma unroll
  for (int k = 0; k < 2; k++){
    int e = ti[tok*2 + k];
    int pos = atomicAdd(&fillpos[e], 1);
    tok_id[pos] = tok;
    pgate[pos]  = tg[tok*2 + k];
    pe[pos]     = e;
  }
}

// v[r][k] = gelu(t_r * tw1[e][k] + tb1[e][k])  (bf16)
__global__ __launch_bounds__(256) void k_vgelu(const float* __restrict__ t,
    const float* __restrict__ tw1, const float* __restrict__ tb1,
    const int* __restrict__ tok_id, const int* __restrict__ pe,
    const int* __restrict__ poff, unsigned short* __restrict__ vbuf){
  int idx = blockIdx.x*256 + threadIdx.x;
  int r = idx >> 10, k = idx & (CDIM - 1);
  if (r >= poff[NE]) return;
  int e = pe[r];
  float tv = t[tok_id[r]];
  float u = tv * tw1[(size_t)e*CDIM + k] + tb1[(size_t)e*CDIM + k];
  vbuf[(size_t)r*CDIM + k] = f2bf(gelu_exact(u));
}

// ---------- GEMM1: te = v @ tw2[e] + tb2[e] ----------
__global__ __launch_bounds__(256) void k_gemm_te(
    const unsigned short* __restrict__ vbuf,
    const float* __restrict__ tw2, const float* __restrict__ tb2,
    const int* __restrict__ poff, const int* __restrict__ pe,
    unsigned short* __restrict__ tebuf){
  int r0 = blockIdx.y * BMR;
  if (r0 >= poff[NE]) return;
  int e = pe[r0];
  int n0 = blockIdx.x * 64;
  const float* Bp = tw2 + (size_t)e*CDIM*CDIM;
  __shared__ float As[16][68];
  __shared__ float Bs[16][68];
  int tid = threadIdx.x;
  int tx = tid & 15, ty = tid >> 4;
  int lm = tid >> 2, lk = (tid & 3)*4;
  int bk = tid >> 4, bn = (tid & 15)*4;
  float acc[4][4] = {{0.f}};
  for (int k0 = 0; k0 < CDIM; k0 += 16){
    ushort4 av = *reinterpret_cast<const ushort4*>(vbuf + (size_t)(r0+lm)*CDIM + k0 + lk);
    float4  bv = *reinterpret_cast<const float4*>(Bp + (size_t)(k0+bk)*CDIM + n0 + bn);
    __syncthreads();
    As[lk+0][lm] = bf2f(av.x); As[lk+1][lm] = bf2f(av.y);
    As[lk+2][lm] = bf2f(av.z); As[lk+3][lm] = bf2f(av.w);
    *reinterpret_cast<float4*>(&Bs[bk][bn]) = bv;
    __syncthreads();
    #pragma unroll
    for (int k = 0; k < 16; k++){
      float4 a = *reinterpret_cast<const float4*>(&As[k][ty*4]);
      float4 b = *reinterpret_cast<const float4*>(&Bs[k][tx*4]);
      float am[4] = {a.x,a.y,a.z,a.w}, bn4[4] = {b.x,b.y,b.z,b.w};
      #pragma unroll
      for (int i = 0; i < 4; i++)
        #pragma unroll
        for (int j = 0; j < 4; j++) acc[i][j] += am[i]*bn4[j];
    }
  }
  #pragma unroll
  for (int i = 0; i < 4; i++){
    int r = r0 + ty*4 + i;
    #pragma unroll
    for (int j = 0; j < 4; j++){
      int n = n0 + tx*4 + j;
      tebuf[(size_t)r*CDIM + n] = f2bf(acc[i][j] + tb2[(size_t)e*CDIM + n]);
    }
  }
}

// ---------- GEMM2: h = gelu([x|te] @ mw1[e] + mb1[e]) ----------
__global__ __launch_bounds__(256) void k_gemm_h(
    const float* __restrict__ x, const unsigned short* __restrict__ tebuf,
    const float* __restrict__ mw1, const float* __restrict__ mb1,
    const int* __restrict__ poff, const int* __restrict__ pe,
    const int* __restrict__ tok_id, unsigned short* __restrict__ hbuf){
  int r0 = blockIdx.y * BMR;
  if (r0 >= poff[NE]) return;
  int e = pe[r0];
  int n0 = blockIdx.x * 64;
  const float* Bp = mw1 + (size_t)e*(2*CDIM)*MLPD;
  __shared__ float As[16][68];
  __shared__ float Bs[16][68];
  __shared__ int toks[BMR];
  int tid = threadIdx.x;
  if (tid < BMR) toks[tid] = tok_id[r0 + tid];
  int tx = tid & 15, ty = tid >> 4;
  int lm = tid >> 2, lk = (tid & 3)*4;
  int bk = tid >> 4, bn = (tid & 15)*4;
  float acc[4][4] = {{0.f}};
  __syncthreads();
  for (int k0 = 0; k0 < 2*CDIM; k0 += 16){
    float4 af;
    if (k0 < CDIM){
      af = *reinterpret_cast<const float4*>(x + (size_t)toks[lm]*CDIM + k0 + lk);
    } else {
      ushort4 av = *reinterpret_cast<const ushort4*>(tebuf + (size_t)(r0+lm)*CDIM + (k0 - CDIM) + lk);
      af.x = bf2f(av.x); af.y = bf2f(av.y); af.z = bf2f(av.z); af.w = bf2f(av.w);
    }
    float4 bv = *reinterpret_cast<const float4*>(Bp + (size_t)(k0+bk)*MLPD + n0 + bn);
    __syncthreads();
    As[lk+0][lm] = af.x; As[lk+1][lm] = af.y;
    As[lk+2][lm] = af.z; As[lk+3][lm] = af.w;
    *reinterpret_cast<float4*>(&Bs[bk][bn]) = bv;
    __syncthreads();
    #pragma unroll
    for (int k = 0; k < 16; k++){
      float4 a = *reinterpret_cast<const float4*>(&As[k][ty*4]);
      float4 b = *reinterpret_cast<const float4*>(&Bs[k][tx*4]);
      float am[4] = {a.x,a.y,a.z,a.w}, bn4[4] = {b.x,b.y,b.z,b.w};
      #pragma unroll
      for (int i = 0; i < 4; i++)
        #pragma unroll
        for (int j = 0; j < 4; j++) acc[i][j] += am[i]*bn4[j];
    }
  }
  #pragma unroll
  for (int i = 0; i < 4; i++){
    int r = r0 + ty*4 + i;
    #pragma unroll
    for (int j = 0; j < 4; j++){
      int n = n0 + tx*4 + j;
      hbuf[(size_t)r*MLPD + n] = f2bf(gelu_exact(acc[i][j] + mb1[(size_t)e*MLPD + n]));
    }
  }
}

// ---------- GEMM3: out[tok] += gate * (h @ mw2[e] + mb2[e]) ----------
__global__ __launch_bounds__(256) void k_gemm_out(
    const unsigned short* __restrict__ hbuf,
    const float* __restrict__ mw2, const float* __restrict__ mb2,
    const int* __restrict__ poff, const int* __restrict__ pe,
    const int* __restrict__ tok_id, const float* __restrict__ pgate,
    float* __restrict__ out){
  int r0 = blockIdx.y * BMR;
  if (r0 >= poff[NE]) return;
  int e = pe[r0];
  int n0 = blockIdx.x * 64;
  const float* Bp = mw2 + (size_t)e*MLPD*CDIM;
  __shared__ float As[16][68];
  __shared__ float Bs[16][68];
  __shared__ int   toks[BMR];
  __shared__ float gts[BMR];
  int tid = threadIdx.x;
  if (tid < BMR){ toks[tid] = tok_id[r0 + tid]; gts[tid] = pgate[r0 + tid]; }
  int tx = tid & 15, ty = tid >> 4;
  int lm = tid >> 2, lk = (tid & 3)*4;
  int bk = tid >> 4, bn = (tid & 15)*4;
  float acc[4][4] = {{0.f}};
  __syncthreads();
  for (int k0 = 0; k0 < MLPD; k0 += 16){
    ushort4 av = *reinterpret_cast<const ushort4*>(hbuf + (size_t)(r0+lm)*MLPD + k0 + lk);
    float4  bv = *reinterpret_cast<const float4*>(Bp + (size_t)(k0+bk)*CDIM + n0 + bn);
    __syncthreads();
    As[lk+0][lm] = bf2f(av.x); As[lk+1][lm] = bf2f(av.y);
    As[lk+2][lm] = bf2f(av.z); As[lk+3][lm] = bf2f(av.w);
    *reinterpret_cast<float4*>(&Bs[bk][bn]) = bv;
    __syncthreads();
    #pragma unroll
    for (int k = 0; k < 16; k++){
      float4 a = *reinterpret_cast<const float4*>(&As[k][ty*4]);
      float4 b = *reinterpret_cast<const float4*>(&Bs[k][tx*4]);
      float am[4] = {a.x,a.y,a.z,a.w}, bn4[4] = {b.x,b.y,b.z,b.w};
      #pragma unroll
      for (int i = 0; i < 4; i++)
        #pragma unroll
        for (int j = 0; j < 4; j++) acc[i][j] += am[i]*bn4[j];
    }
  }
  #pragma unroll
  for (int i = 0; i < 4; i++){
    int rl = ty*4 + i;
    int tok = toks[rl];
    float g = gts[rl];           // padding rows: g==0 -> adds 0 to out[0][*]
    #pragma unroll
    for (int j = 0; j < 4; j++){
      int n = n0 + tx*4 + j;
      float val = acc[i][j] + mb2[(size_t)e*CDIM + n];
      atomicAdd(&out[(size_t)tok*CDIM + n], g*val);
    }
  }
}

// ---------- loss ----------
__global__ void k_loss(const float* __restrict__ loadsum, float* __restrict__ outp){
  if (threadIdx.x == 0 && blockIdx.x == 0){
    float m = 0.f;
    for (int e = 0; e < NE; e++) m += loadsum[e];
    m *= (1.f/NE);
    float v = 0.f;
    for (int e = 0; e < NE; e++){ float d = loadsum[e] - m; v += d*d; }
    v *= (1.f/(NE-1));            // ddof=1
    float bal = v / (m*m + 1e-10f);
    outp[0] = 2.f * bal;          // weight_balance + load_balance
  }
}

extern "C" void kernel_launch(void* const* d_in, const int* in_sizes, int n_in,
                              void* d_out, int out_size, void* d_ws, size_t ws_size,
                              hipStream_t stream){
  const float* x      = (const float*)d_in[0];
  const float* p      = (const float*)d_in[1];
  const float* t      = (const float*)d_in[2];
  const float* te_w1  = (const float*)d_in[3];
  const float* te_b1  = (const float*)d_in[4];
  const float* te_w2  = (const float*)d_in[5];
  const float* te_b2  = (const float*)d_in[6];
  const float* gate_w = (const float*)d_in[7];
  const float* ex_tw1 = (const float*)d_in[8];
  const float* ex_tb1 = (const float*)d_in[9];
  const float* ex_tw2 = (const float*)d_in[10];
  const float* ex_tb2 = (const float*)d_in[11];
  const float* ex_mw1 = (const float*)d_in[12];
  const float* ex_mb1 = (const float*)d_in[13];
  const float* ex_mw2 = (const float*)d_in[14];
  const float* ex_mb2 = (const float*)d_in[15];
  float* out = (float*)d_out;

  // workspace carve (~89.5 MB). hbuf aliases vbuf (v is dead before h is written).
  char* ws = (char*)d_ws;
  size_t off = 0;
  auto take = [&](size_t b){ size_t r = off; off = (off + b + 255) & ~(size_t)255; return r; };
  int*   counts  = (int*)  (ws + take(NE*sizeof(int)));
  int*   fillpos = (int*)  (ws + take(NE*sizeof(int)));
  int*   poff    = (int*)  (ws + take((NE+1)*sizeof(int)));
  float* loadsum = (float*)(ws + take(NE*sizeof(float)));
  float* M2      = (float*)(ws + take((size_t)CDIM*NE*sizeof(float)));
  float* c2      = (float*)(ws + take(NE*sizeof(float)));
  int*   ti      = (int*)  (ws + take((size_t)TTOK*2*sizeof(int)));
  float* tg      = (float*)(ws + take((size_t)TTOK*2*sizeof(float)));
  int*   tok_id  = (int*)  (ws + take((size_t)PCAP*sizeof(int)));
  float* pgate   = (float*)(ws + take((size_t)PCAP*sizeof(float)));
  int*   pe      = (int*)  (ws + take((size_t)PCAP*sizeof(int)));
  unsigned short* vbuf  = (unsigned short*)(ws + take((size_t)PCAP*MLPD*2)); // union: v then h
  unsigned short* hbuf  = vbuf;
  unsigned short* tebuf = (unsigned short*)(ws + take((size_t)PCAP*CDIM*2));

  int nOut = TTOK*CDIM + 1;
  k_zero<<<dim3((nOut + 255)/256), dim3(256), 0, stream>>>(out, nOut, counts, loadsum);
  k_m2<<<dim3((CDIM*NE + NE + 255)/256), dim3(256), 0, stream>>>(te_w2, te_b2, gate_w, M2, c2);
  k_gate<<<dim3(TTOK), dim3(256), 0, stream>>>(x, p, t, te_w1, te_b1, gate_w, M2, c2,
                                               ti, tg, counts, loadsum);
  k_scan<<<dim3(1), dim3(256), 0, stream>>>(counts, poff, fillpos, tok_id, pgate, pe);
  k_fill<<<dim3((TTOK + 255)/256), dim3(256), 0, stream>>>(ti, tg, fillpos, tok_id, pgate, pe);
  k_vgelu<<<dim3((PCAP*CDIM)/256), dim3(256), 0, stream>>>(t, ex_tw1, ex_tb1, tok_id, pe, poff, vbuf);
  k_gemm_te<<<dim3(CDIM/64, PCAP/BMR), dim3(256), 0, stream>>>(vbuf, ex_tw2, ex_tb2, poff, pe, tebuf);
  k_gemm_h<<<dim3(MLPD/64, PCAP/BMR), dim3(256), 0, stream>>>(x, tebuf, ex_mw1, ex_mb1,
                                                              poff, pe, tok_id, hbuf);
  k_gemm_out<<<dim3(CDIM/64, PCAP/BMR), dim3(256), 0, stream>>>(hbuf, ex_mw2, ex_mb2,
                                                                poff, pe, tok_id, pgate, out);
  k_loss<<<dim3(1), dim3(64), 0, stream>>>(loadsum, out + (size_t)TTOK*CDIM);
}

// Round 2
// 1242.421 us; speedup vs baseline: 2.8857x; 2.8857x over previous
//
#include <hip/hip_runtime.h>
#include <cmath>

#define TTOK 4096
#define CDIM 1024
#define NE 8
#define MLPD 4096
#define PCAP (2*TTOK + NE*128)   // 9216 padded token-expert pairs max (128-granular)

typedef __attribute__((ext_vector_type(8))) short short8;
typedef __attribute__((ext_vector_type(4))) float float4v;

// ---------- helpers ----------
__device__ __forceinline__ float bf2f(unsigned short h){
  return __uint_as_float(((unsigned int)h) << 16);
}
__device__ __forceinline__ unsigned short f2bf(float f){
  unsigned int u = __float_as_uint(f);
  u += 0x7FFFu + ((u >> 16) & 1u);   // RNE
  return (unsigned short)(u >> 16);
}
__device__ __forceinline__ float gelu_exact(float x){
  return 0.5f * x * (1.0f + erff(x * 0.70710678118654752f));
}
// async global->LDS, 16B per lane; LDS dest = wave-uniform base + lane*16
__device__ __forceinline__ void gld16(const void* g, void* l){
  __builtin_amdgcn_global_load_lds((const __attribute__((address_space(1))) void*)g,
                                   (__attribute__((address_space(3))) void*)l, 16, 0, 0);
}

// ---------- init ----------
__global__ __launch_bounds__(256) void k_zero(float* out, int n, int* counts, float* loadsum){
  int i = blockIdx.x*256 + threadIdx.x;
  if (i < n) out[i] = 0.f;
  if (i < NE){ counts[i] = 0; loadsum[i] = 0.f; }
}

// M2[i][e] = sum_j te_w2[i][j] * gate_w[2C+j][e];  c2[e] = sum_j te_b2[j]*gate_w[2C+j][e]
__global__ __launch_bounds__(256) void k_m2(const float* __restrict__ te_w2,
    const float* __restrict__ te_b2, const float* __restrict__ gate_w,
    float* __restrict__ M2, float* __restrict__ c2){
  int idx = blockIdx.x*256 + threadIdx.x;
  if (idx < CDIM*NE){
    int i = idx >> 3, e = idx & 7;
    float s = 0.f;
    for (int j = 0; j < CDIM; j++)
      s += te_w2[(size_t)i*CDIM + j] * gate_w[(size_t)(2*CDIM + j)*NE + e];
    M2[idx] = s;
  } else if (idx < CDIM*NE + NE){
    int e = idx - CDIM*NE;
    float s = 0.f;
    for (int j = 0; j < CDIM; j++)
      s += te_b2[j] * gate_w[(size_t)(2*CDIM + j)*NE + e];
    c2[e] = s;
  }
}

// ---------- weight conversion ----------
// x fp32 -> bf16 (no transpose)
__global__ __launch_bounds__(256) void k_cvt_x(const float* __restrict__ x,
                                               unsigned short* __restrict__ xb, int n4){
  int i = blockIdx.x*256 + threadIdx.x;
  if (i >= n4) return;
  float4 v = reinterpret_cast<const float4*>(x)[i];
  ushort4 o;
  o.x = f2bf(v.x); o.y = f2bf(v.y); o.z = f2bf(v.z); o.w = f2bf(v.w);
  reinterpret_cast<ushort4*>(xb)[i] = o;
}

// W [E][K][N] fp32 -> Wt [E][N][K] bf16 (transpose-convert, 32x32 LDS tiles)
__global__ __launch_bounds__(256) void k_cvt_w(const float* __restrict__ W,
    unsigned short* __restrict__ Wt, int K, int N){
  __shared__ float tile[32][33];
  int kb = blockIdx.x*32, nb = blockIdx.y*32, e = blockIdx.z;
  const float* Wp = W + (size_t)e*K*N;
  unsigned short* Wo = Wt + (size_t)e*K*N;
  int tx = threadIdx.x & 31, ty = threadIdx.x >> 5;   // ty 0..7
  #pragma unroll
  for (int i = 0; i < 32; i += 8)
    tile[ty+i][tx] = Wp[(size_t)(kb+ty+i)*N + nb + tx];
  __syncthreads();
  #pragma unroll
  for (int i = 0; i < 32; i += 8)
    Wo[(size_t)(nb+ty+i)*K + kb + tx] = f2bf(tile[tx][ty+i]);
}

// ---------- gating ----------
__global__ __launch_bounds__(256) void k_gate(const float* __restrict__ x,
    const float* __restrict__ p, const float* __restrict__ t,
    const float* __restrict__ te_w1, const float* __restrict__ te_b1,
    const float* __restrict__ gate_w, const float* __restrict__ M2,
    const float* __restrict__ c2,
    int* __restrict__ ti, float* __restrict__ tg,
    int* __restrict__ counts, float* __restrict__ loadsum){
  int tok = blockIdx.x, tid = threadIdx.x;
  float tv = t[tok];
  float acc[NE];
  #pragma unroll
  for (int e = 0; e < NE; e++) acc[e] = 0.f;
  for (int j = tid; j < CDIM; j += 256){
    float xv = x[(size_t)tok*CDIM + j];
    float pv = p[(size_t)tok*CDIM + j];
    float vv = gelu_exact(tv*te_w1[j] + te_b1[j]);
    const float* g0 = gate_w + (size_t)j*NE;
    const float* g1 = gate_w + (size_t)(CDIM + j)*NE;
    const float* m2 = M2 + (size_t)j*NE;
    #pragma unroll
    for (int e = 0; e < NE; e++) acc[e] += xv*g0[e] + pv*g1[e] + vv*m2[e];
  }
  __shared__ float red[256][NE];
  #pragma unroll
  for (int e = 0; e < NE; e++) red[tid][e] = acc[e];
  __syncthreads();
  for (int s = 128; s > 0; s >>= 1){
    if (tid < s){
      #pragma unroll
      for (int e = 0; e < NE; e++) red[tid][e] += red[tid+s][e];
    }
    __syncthreads();
  }
  if (tid == 0){
    float lg[NE];
    #pragma unroll
    for (int e = 0; e < NE; e++) lg[e] = red[0][e] + c2[e];
    int i1 = 0; float l1 = lg[0];
    #pragma unroll
    for (int e = 1; e < NE; e++) if (lg[e] > l1){ l1 = lg[e]; i1 = e; }
    int i2 = -1; float l2 = -3.4e38f;
    #pragma unroll
    for (int e = 0; e < NE; e++) if (e != i1 && lg[e] > l2){ l2 = lg[e]; i2 = e; }
    float ex  = expf(l2 - l1);
    float g1v = 1.f/(1.f + ex);
    float g2v = ex/(1.f + ex);
    ti[tok*2]   = i1; ti[tok*2+1] = i2;
    tg[tok*2]   = g1v; tg[tok*2+1] = g2v;
    atomicAdd(&counts[i1], 1);  atomicAdd(&counts[i2], 1);
    atomicAdd(&loadsum[i1], g1v); atomicAdd(&loadsum[i2], g2v);
  }
}

// ---------- dispatch ----------
__global__ __launch_bounds__(256) void k_scan(const int* __restrict__ counts,
    int* __restrict__ poff, int* __restrict__ fillpos,
    int* __restrict__ tok_id, float* __restrict__ pgate, int* __restrict__ pe, int padg){
  __shared__ int so[NE+1];
  __shared__ int sc[NE];
  if (threadIdx.x == 0){
    int o = 0;
    for (int e = 0; e < NE; e++){
      so[e] = o; poff[e] = o; fillpos[e] = o;
      sc[e] = counts[e];
      o += (sc[e] + padg - 1) & ~(padg - 1);
    }
    so[NE] = o; poff[NE] = o;
  }
  __syncthreads();
  for (int e = 0; e < NE; e++){
    int s = so[e] + sc[e], en = so[e+1];
    for (int i = s + (int)threadIdx.x; i < en; i += 256){
      tok_id[i] = 0; pgate[i] = 0.f; pe[i] = e;   // dummy rows: gate 0
    }
  }
}

__global__ __launch_bounds__(256) void k_fill(const int* __restrict__ ti,
    const float* __restrict__ tg, int* __restrict__ fillpos,
    int* __restrict__ tok_id, float* __restrict__ pgate, int* __restrict__ pe){
  int tok = blockIdx.x*256 + threadIdx.x;
  if (tok >= TTOK) return;
  #pragma unroll
  for (int k = 0; k < 2; k++){
    int e = ti[tok*2 + k];
    int pos = atomicAdd(&fillpos[e], 1);
    tok_id[pos] = tok;
    pgate[pos]  = tg[tok*2 + k];
    pe[pos]     = e;
  }
}

// v[r][k] = gelu(t_r * tw1[e][k] + tb1[e][k])  (bf16)
__global__ __launch_bounds__(256) void k_vgelu(const float* __restrict__ t,
    const float* __restrict__ tw1, const float* __restrict__ tb1,
    const int* __restrict__ tok_id, const int* __restrict__ pe,
    const int* __restrict__ poff, unsigned short* __restrict__ vbuf){
  int idx = blockIdx.x*256 + threadIdx.x;
  int r = idx >> 10, k = idx & (CDIM - 1);
  if (r >= poff[NE]) return;
  int e = pe[r];
  float tv = t[tok_id[r]];
  float u = tv * tw1[(size_t)e*CDIM + k] + tb1[(size_t)e*CDIM + k];
  vbuf[(size_t)r*CDIM + k] = f2bf(gelu_exact(u));
}

// =========================================================================
// MFMA GEMMs: 128x128 tile, BK=32, 4 waves, 16x16x32 bf16.
// A LDS [128][32] bf16 (m-major), B LDS [128][32] bf16 (n-major; weights
// are pre-transposed to [N][K]). Staging via global_load_lds width 16.
// Frag layouts (measured): A[m=lane&15][k=(lane>>4)*8+j];
// B[n=lane&15][k=(lane>>4)*8+j]; C/D col=lane&15, row=(lane>>4)*4+reg.
// =========================================================================

// GEMM1: te = v @ tw2[e] + tb2[e]   (K=1024, N=1024)
__global__ __launch_bounds__(256,2) void k_mfma_te(
    const unsigned short* __restrict__ vbuf,
    const unsigned short* __restrict__ Wt1, const float* __restrict__ tb2,
    const int* __restrict__ poff, const int* __restrict__ pe,
    unsigned short* __restrict__ tebuf){
  __shared__ unsigned short As[128*32];
  __shared__ unsigned short Bs[128*32];
  int r0 = blockIdx.y * 128;
  if (r0 >= poff[NE]) return;
  int e = pe[r0];
  int n0 = blockIdx.x * 128;
  int tid = threadIdx.x, lane = tid & 63, w = tid >> 6;
  const unsigned short* Bp = Wt1 + (size_t)e*CDIM*CDIM;   // [N=1024][K=1024]
  int mb = (w&1)*64, nb = (w>>1)*64;
  float4v acc[4][4];
  #pragma unroll
  for (int i=0;i<4;i++)
    #pragma unroll
    for (int j=0;j<4;j++) acc[i][j] = (float4v){0.f,0.f,0.f,0.f};
  int rowA = w*32 + (lane>>2);
  int ck = (lane&3)*8;
  for (int k0 = 0; k0 < CDIM; k0 += 32){
    __syncthreads();
    unsigned short* lA = As + (w*32)*32;
    unsigned short* lB = Bs + (w*32)*32;
    gld16(vbuf + (size_t)(r0+rowA)*CDIM + k0 + ck, lA);
    gld16(vbuf + (size_t)(r0+rowA+16)*CDIM + k0 + ck, lA + 16*32);
    gld16(Bp + (size_t)(n0+rowA)*CDIM + k0 + ck, lB);
    gld16(Bp + (size_t)(n0+rowA+16)*CDIM + k0 + ck, lB + 16*32);
    __syncthreads();
    short8 a[4], b[4];
    #pragma unroll
    for (int mi=0;mi<4;mi++) a[mi] = *(const short8*)(As + (mb+mi*16+(lane&15))*32 + (lane>>4)*8);
    #pragma unroll
    for (int ni=0;ni<4;ni++) b[ni] = *(const short8*)(Bs + (nb+ni*16+(lane&15))*32 + (lane>>4)*8);
    #pragma unroll
    for (int mi=0;mi<4;mi++)
      #pragma unroll
      for (int ni=0;ni<4;ni++)
        acc[mi][ni] = __builtin_amdgcn_mfma_f32_16x16x32_bf16(a[mi], b[ni], acc[mi][ni], 0, 0, 0);
  }
  int col = lane & 15, rq = (lane>>4)*4;
  const float* bias = tb2 + (size_t)e*CDIM + n0;
  #pragma unroll
  for (int mi=0;mi<4;mi++)
    #pragma unroll
    for (int ni=0;ni<4;ni++){
      int n = nb + ni*16 + col;
      #pragma unroll
      for (int rg=0;rg<4;rg++){
        int r = r0 + mb + mi*16 + rq + rg;
        tebuf[(size_t)r*CDIM + n0 + n] = f2bf(acc[mi][ni][rg] + bias[n]);
      }
    }
}

// GEMM2: h = gelu([x|te] @ mw1[e] + mb1[e])   (K=2048, N=4096)
__global__ __launch_bounds__(256,2) void k_mfma_h(
    const unsigned short* __restrict__ xb, const unsigned short* __restrict__ tebuf,
    const unsigned short* __restrict__ Wt2, const float* __restrict__ mb1,
    const int* __restrict__ poff, const int* __restrict__ pe,
    const int* __restrict__ tok_id, unsigned short* __restrict__ hbuf){
  __shared__ unsigned short As[128*32];
  __shared__ unsigned short Bs[128*32];
  __shared__ int toks[128];
  int r0 = blockIdx.y * 128;
  if (r0 >= poff[NE]) return;
  int e = pe[r0];
  int n0 = blockIdx.x * 128;
  int tid = threadIdx.x, lane = tid & 63, w = tid >> 6;
  if (tid < 128) toks[tid] = tok_id[r0 + tid];
  const unsigned short* Bp = Wt2 + (size_t)e*(2*CDIM)*MLPD;   // [N=4096][K=2048]
  int mb = (w&1)*64, nb = (w>>1)*64;
  float4v acc[4][4];
  #pragma unroll
  for (int i=0;i<4;i++)
    #pragma unroll
    for (int j=0;j<4;j++) acc[i][j] = (float4v){0.f,0.f,0.f,0.f};
  int rowA = w*32 + (lane>>2);
  int ck = (lane&3)*8;
  for (int k0 = 0; k0 < 2*CDIM; k0 += 32){
    __syncthreads();
    unsigned short* lA = As + (w*32)*32;
    unsigned short* lB = Bs + (w*32)*32;
    if (k0 < CDIM){
      int tok0 = toks[rowA], tok1 = toks[rowA+16];
      gld16(xb + (size_t)tok0*CDIM + k0 + ck, lA);
      gld16(xb + (size_t)tok1*CDIM + k0 + ck, lA + 16*32);
    } else {
      gld16(tebuf + (size_t)(r0+rowA)*CDIM + (k0-CDIM) + ck, lA);
      gld16(tebuf + (size_t)(r0+rowA+16)*CDIM + (k0-CDIM) + ck, lA + 16*32);
    }
    gld16(Bp + (size_t)(n0+rowA)*(2*CDIM) + k0 + ck, lB);
    gld16(Bp + (size_t)(n0+rowA+16)*(2*CDIM) + k0 + ck, lB + 16*32);
    __syncthreads();
    short8 a[4], b[4];
    #pragma unroll
    for (int mi=0;mi<4;mi++) a[mi] = *(const short8*)(As + (mb+mi*16+(lane&15))*32 + (lane>>4)*8);
    #pragma unroll
    for (int ni=0;ni<4;ni++) b[ni] = *(const short8*)(Bs + (nb+ni*16+(lane&15))*32 + (lane>>4)*8);
    #pragma unroll
    for (int mi=0;mi<4;mi++)
      #pragma unroll
      for (int ni=0;ni<4;ni++)
        acc[mi][ni] = __builtin_amdgcn_mfma_f32_16x16x32_bf16(a[mi], b[ni], acc[mi][ni], 0, 0, 0);
  }
  int col = lane & 15, rq = (lane>>4)*4;
  const float* bias = mb1 + (size_t)e*MLPD + n0;
  #pragma unroll
  for (int mi=0;mi<4;mi++)
    #pragma unroll
    for (int ni=0;ni<4;ni++){
      int n = nb + ni*16 + col;
      #pragma unroll
      for (int rg=0;rg<4;rg++){
        int r = r0 + mb + mi*16 + rq + rg;
        hbuf[(size_t)r*MLPD + n0 + n] = f2bf(gelu_exact(acc[mi][ni][rg] + bias[n]));
      }
    }
}

// GEMM3: out[tok] += gate * (h @ mw2[e] + mb2[e])   (K=4096, N=1024)
__global__ __launch_bounds__(256,2) void k_mfma_out(
    const unsigned short* __restrict__ hbuf,
    const unsigned short* __restrict__ Wt3, const float* __restrict__ mb2,
    const int* __restrict__ poff, const int* __restrict__ pe,
    const int* __restrict__ tok_id, const float* __restrict__ pgate,
    float* __restrict__ out){
  __shared__ unsigned short As[128*32];
  __shared__ unsigned short Bs[128*32];
  __shared__ int   toks[128];
  __shared__ float gts[128];
  int r0 = blockIdx.y * 128;
  if (r0 >= poff[NE]) return;
  int e = pe[r0];
  int n0 = blockIdx.x * 128;
  int tid = threadIdx.x, lane = tid & 63, w = tid >> 6;
  if (tid < 128){ toks[tid] = tok_id[r0 + tid]; gts[tid] = pgate[r0 + tid]; }
  const unsigned short* Bp = Wt3 + (size_t)e*MLPD*CDIM;   // [N=1024][K=4096]
  int mb = (w&1)*64, nb = (w>>1)*64;
  float4v acc[4][4];
  #pragma unroll
  for (int i=0;i<4;i++)
    #pragma unroll
    for (int j=0;j<4;j++) acc[i][j] = (float4v){0.f,0.f,0.f,0.f};
  int rowA = w*32 + (lane>>2);
  int ck = (lane&3)*8;
  for (int k0 = 0; k0 < MLPD; k0 += 32){
    __syncthreads();
    unsigned short* lA = As + (w*32)*32;
    unsigned short* lB = Bs + (w*32)*32;
    gld16(hbuf + (size_t)(r0+rowA)*MLPD + k0 + ck, lA);
    gld16(hbuf + (size_t)(r0+rowA+16)*MLPD + k0 + ck, lA + 16*32);
    gld16(Bp + (size_t)(n0+rowA)*MLPD + k0 + ck, lB);
    gld16(Bp + (size_t)(n0+rowA+16)*MLPD + k0 + ck, lB + 16*32);
    __syncthreads();
    short8 a[4], b[4];
    #pragma unroll
    for (int mi=0;mi<4;mi++) a[mi] = *(const short8*)(As + (mb+mi*16+(lane&15))*32 + (lane>>4)*8);
    #pragma unroll
    for (int ni=0;ni<4;ni++) b[ni] = *(const short8*)(Bs + (nb+ni*16+(lane&15))*32 + (lane>>4)*8);
    #pragma unroll
    for (int mi=0;mi<4;mi++)
      #pragma unroll
      for (int ni=0;ni<4;ni++)
        acc[mi][ni] = __builtin_amdgcn_mfma_f32_16x16x32_bf16(a[mi], b[ni], acc[mi][ni], 0, 0, 0);
  }
  int col = lane & 15, rq = (lane>>4)*4;
  const float* bias = mb2 + (size_t)e*CDIM + n0;
  #pragma unroll
  for (int mi=0;mi<4;mi++)
    #pragma unroll
    for (int ni=0;ni<4;ni++){
      int n = nb + ni*16 + col;
      #pragma unroll
      for (int rg=0;rg<4;rg++){
        int rl = mb + mi*16 + rq + rg;
        float g = gts[rl];
        float val = acc[mi][ni][rg] + bias[n];
        atomicAdd(&out[(size_t)toks[rl]*CDIM + n0 + n], g*val);
      }
    }
}

// =========================================================================
// Fallback fp32 path (round-1 kernels, 64-row tiles) — used if ws too small
// =========================================================================
__global__ __launch_bounds__(256) void k_gemm_te_f(
    const unsigned short* __restrict__ vbuf,
    const float* __restrict__ tw2, const float* __restrict__ tb2,
    const int* __restrict__ poff, const int* __restrict__ pe,
    unsigned short* __restrict__ tebuf){
  int r0 = blockIdx.y * 64;
  if (r0 >= poff[NE]) return;
  int e = pe[r0];
  int n0 = blockIdx.x * 64;
  const float* Bp = tw2 + (size_t)e*CDIM*CDIM;
  __shared__ float As[16][68];
  __shared__ float Bs[16][68];
  int tid = threadIdx.x;
  int tx = tid & 15, ty = tid >> 4;
  int lm = tid >> 2, lk = (tid & 3)*4;
  int bk = tid >> 4, bn = (tid & 15)*4;
  float acc[4][4] = {{0.f}};
  for (int k0 = 0; k0 < CDIM; k0 += 16){
    ushort4 av = *reinterpret_cast<const ushort4*>(vbuf + (size_t)(r0+lm)*CDIM + k0 + lk);
    float4  bv = *reinterpret_cast<const float4*>(Bp + (size_t)(k0+bk)*CDIM + n0 + bn);
    __syncthreads();
    As[lk+0][lm] = bf2f(av.x); As[lk+1][lm] = bf2f(av.y);
    As[lk+2][lm] = bf2f(av.z); As[lk+3][lm] = bf2f(av.w);
    *reinterpret_cast<float4*>(&Bs[bk][bn]) = bv;
    __syncthreads();
    #pragma unroll
    for (int k = 0; k < 16; k++){
      float4 a = *reinterpret_cast<const float4*>(&As[k][ty*4]);
      float4 b = *reinterpret_cast<const float4*>(&Bs[k][tx*4]);
      float am[4] = {a.x,a.y,a.z,a.w}, bn4[4] = {b.x,b.y,b.z,b.w};
      #pragma unroll
      for (int i = 0; i < 4; i++)
        #pragma unroll
        for (int j = 0; j < 4; j++) acc[i][j] += am[i]*bn4[j];
    }
  }
  #pragma unroll
  for (int i = 0; i < 4; i++){
    int r = r0 + ty*4 + i;
    #pragma unroll
    for (int j = 0; j < 4; j++){
      int n = n0 + tx*4 + j;
      tebuf[(size_t)r*CDIM + n] = f2bf(acc[i][j] + tb2[(size_t)e*CDIM + n]);
    }
  }
}

__global__ __launch_bounds__(256) void k_gemm_h_f(
    const float* __restrict__ x, const unsigned short* __restrict__ tebuf,
    const float* __restrict__ mw1, const float* __restrict__ mb1,
    const int* __restrict__ poff, const int* __restrict__ pe,
    const int* __restrict__ tok_id, unsigned short* __restrict__ hbuf){
  int r0 = blockIdx.y * 64;
  if (r0 >= poff[NE]) return;
  int e = pe[r0];
  int n0 = blockIdx.x * 64;
  const float* Bp = mw1 + (size_t)e*(2*CDIM)*MLPD;
  __shared__ float As[16][68];
  __shared__ float Bs[16][68];
  __shared__ int toks[64];
  int tid = threadIdx.x;
  if (tid < 64) toks[tid] = tok_id[r0 + tid];
  int tx = tid & 15, ty = tid >> 4;
  int lm = tid >> 2, lk = (tid & 3)*4;
  int bk = tid >> 4, bn = (tid & 15)*4;
  float acc[4][4] = {{0.f}};
  __syncthreads();
  for (int k0 = 0; k0 < 2*CDIM; k0 += 16){
    float4 af;
    if (k0 < CDIM){
      af = *reinterpret_cast<const float4*>(x + (size_t)toks[lm]*CDIM + k0 + lk);
    } else {
      ushort4 av = *reinterpret_cast<const ushort4*>(tebuf + (size_t)(r0+lm)*CDIM + (k0 - CDIM) + lk);
      af.x = bf2f(av.x); af.y = bf2f(av.y); af.z = bf2f(av.z); af.w = bf2f(av.w);
    }
    float4 bv = *reinterpret_cast<const float4*>(Bp + (size_t)(k0+bk)*MLPD + n0 + bn);
    __syncthreads();
    As[lk+0][lm] = af.x; As[lk+1][lm] = af.y;
    As[lk+2][lm] = af.z; As[lk+3][lm] = af.w;
    *reinterpret_cast<float4*>(&Bs[bk][bn]) = bv;
    __syncthreads();
    #pragma unroll
    for (int k = 0; k < 16; k++){
      float4 a = *reinterpret_cast<const float4*>(&As[k][ty*4]);
      float4 b = *reinterpret_cast<const float4*>(&Bs[k][tx*4]);
      float am[4] = {a.x,a.y,a.z,a.w}, bn4[4] = {b.x,b.y,b.z,b.w};
      #pragma unroll
      for (int i = 0; i < 4; i++)
        #pragma unroll
        for (int j = 0; j < 4; j++) acc[i][j] += am[i]*bn4[j];
    }
  }
  #pragma unroll
  for (int i = 0; i < 4; i++){
    int r = r0 + ty*4 + i;
    #pragma unroll
    for (int j = 0; j < 4; j++){
      int n = n0 + tx*4 + j;
      hbuf[(size_t)r*MLPD + n] = f2bf(gelu_exact(acc[i][j] + mb1[(size_t)e*MLPD + n]));
    }
  }
}

__global__ __launch_bounds__(256) void k_gemm_out_f(
    const unsigned short* __restrict__ hbuf,
    const float* __restrict__ mw2, const float* __restrict__ mb2,
    const int* __restrict__ poff, const int* __restrict__ pe,
    const int* __restrict__ tok_id, const float* __restrict__ pgate,
    float* __restrict__ out){
  int r0 = blockIdx.y * 64;
  if (r0 >= poff[NE]) return;
  int e = pe[r0];
  int n0 = blockIdx.x * 64;
  const float* Bp = mw2 + (size_t)e*MLPD*CDIM;
  __shared__ float As[16][68];
  __shared__ float Bs[16][68];
  __shared__ int   toks[64];
  __shared__ float gts[64];
  int tid = threadIdx.x;
  if (tid < 64){ toks[tid] = tok_id[r0 + tid]; gts[tid] = pgate[r0 + tid]; }
  int tx = tid & 15, ty = tid >> 4;
  int lm = tid >> 2, lk = (tid & 3)*4;
  int bk = tid >> 4, bn = (tid & 15)*4;
  float acc[4][4] = {{0.f}};
  __syncthreads();
  for (int k0 = 0; k0 < MLPD; k0 += 16){
    ushort4 av = *reinterpret_cast<const ushort4*>(hbuf + (size_t)(r0+lm)*MLPD + k0 + lk);
    float4  bv = *reinterpret_cast<const float4*>(Bp + (size_t)(k0+bk)*CDIM + n0 + bn);
    __syncthreads();
    As[lk+0][lm] = bf2f(av.x); As[lk+1][lm] = bf2f(av.y);
    As[lk+2][lm] = bf2f(av.z); As[lk+3][lm] = bf2f(av.w);
    *reinterpret_cast<float4*>(&Bs[bk][bn]) = bv;
    __syncthreads();
    #pragma unroll
    for (int k = 0; k < 16; k++){
      float4 a = *reinterpret_cast<const float4*>(&As[k][ty*4]);
      float4 b = *reinterpret_cast<const float4*>(&Bs[k][tx*4]);
      float am[4] = {a.x,a.y,a.z,a.w}, bn4[4] = {b.x,b.y,b.z,b.w};
      #pragma unroll
      for (int i = 0; i < 4; i++)
        #pragma unroll
        for (int j = 0; j < 4; j++) acc[i][j] += am[i]*bn4[j];
    }
  }
  #pragma unroll
  for (int i = 0; i < 4; i++){
    int rl = ty*4 + i;
    int tok = toks[rl];
    float g = gts[rl];
    #pragma unroll
    for (int j = 0; j < 4; j++){
      int n = n0 + tx*4 + j;
      float val = acc[i][j] + mb2[(size_t)e*CDIM + n];
      atomicAdd(&out[(size_t)tok*CDIM + n], g*val);
    }
  }
}

// ---------- loss ----------
__global__ void k_loss(const float* __restrict__ loadsum, float* __restrict__ outp){
  if (threadIdx.x == 0 && blockIdx.x == 0){
    float m = 0.f;
    for (int e = 0; e < NE; e++) m += loadsum[e];
    m *= (1.f/NE);
    float v = 0.f;
    for (int e = 0; e < NE; e++){ float d = loadsum[e] - m; v += d*d; }
    v *= (1.f/(NE-1));
    float bal = v / (m*m + 1e-10f);
    outp[0] = 2.f * bal;
  }
}

extern "C" void kernel_launch(void* const* d_in, const int* in_sizes, int n_in,
                              void* d_out, int out_size, void* d_ws, size_t ws_size,
                              hipStream_t stream){
  const float* x      = (const float*)d_in[0];
  const float* p      = (const float*)d_in[1];
  const float* t      = (const float*)d_in[2];
  const float* te_w1  = (const float*)d_in[3];
  const float* te_b1  = (const float*)d_in[4];
  const float* te_w2  = (const float*)d_in[5];
  const float* te_b2  = (const float*)d_in[6];
  const float* gate_w = (const float*)d_in[7];
  const float* ex_tw1 = (const float*)d_in[8];
  const float* ex_tb1 = (const float*)d_in[9];
  const float* ex_tw2 = (const float*)d_in[10];
  const float* ex_tb2 = (const float*)d_in[11];
  const float* ex_mw1 = (const float*)d_in[12];
  const float* ex_mb1 = (const float*)d_in[13];
  const float* ex_mw2 = (const float*)d_in[14];
  const float* ex_mb2 = (const float*)d_in[15];
  float* out = (float*)d_out;

  char* ws = (char*)d_ws;
  size_t off = 0;
  auto take = [&](size_t b){ size_t r = off; off = (off + b + 255) & ~(size_t)255; return r; };
  // common small buffers
  int*   counts  = (int*)  (ws + take(NE*sizeof(int)));
  int*   fillpos = (int*)  (ws + take(NE*sizeof(int)));
  int*   poff    = (int*)  (ws + take((NE+1)*sizeof(int)));
  float* loadsum = (float*)(ws + take(NE*sizeof(float)));
  float* M2      = (float*)(ws + take((size_t)CDIM*NE*sizeof(float)));
  float* c2      = (float*)(ws + take(NE*sizeof(float)));
  int*   ti      = (int*)  (ws + take((size_t)TTOK*2*sizeof(int)));
  float* tg      = (float*)(ws + take((size_t)TTOK*2*sizeof(float)));
  int*   tok_id  = (int*)  (ws + take((size_t)PCAP*sizeof(int)));
  float* pgate   = (float*)(ws + take((size_t)PCAP*sizeof(float)));
  int*   pe      = (int*)  (ws + take((size_t)PCAP*sizeof(int)));

  // MFMA path needs: xb + hbuf-region + tebuf + Wt2-region (Wt3 aliased into Wt2 later)
  size_t need_mfma = off
      + ((size_t)TTOK*CDIM*2 + 256)        // xb
      + ((size_t)PCAP*MLPD*2 + 256)        // hbuf region (hosts vbuf + Wt1)
      + ((size_t)PCAP*CDIM*2 + 256)        // tebuf
      + ((size_t)NE*2*CDIM*MLPD*2 + 256);  // Wt2 region (>= Wt3)
  bool use_mfma = ws_size >= need_mfma;
  int padg = use_mfma ? 128 : 64;

  int nOut = TTOK*CDIM + 1;
  k_zero<<<dim3((nOut + 255)/256), dim3(256), 0, stream>>>(out, nOut, counts, loadsum);
  k_m2<<<dim3((CDIM*NE + NE + 255)/256), dim3(256), 0, stream>>>(te_w2, te_b2, gate_w, M2, c2);
  k_gate<<<dim3(TTOK), dim3(256), 0, stream>>>(x, p, t, te_w1, te_b1, gate_w, M2, c2,
                                               ti, tg, counts, loadsum);
  k_scan<<<dim3(1), dim3(256), 0, stream>>>(counts, poff, fillpos, tok_id, pgate, pe, padg);
  k_fill<<<dim3((TTOK + 255)/256), dim3(256), 0, stream>>>(ti, tg, fillpos, tok_id, pgate, pe);

  if (use_mfma){
    unsigned short* xb    = (unsigned short*)(ws + take((size_t)TTOK*CDIM*2));
    char*           hreg  = ws + take((size_t)PCAP*MLPD*2);
    unsigned short* vbuf  = (unsigned short*)hreg;                           // [0, 18.9MB)
    unsigned short* Wt1   = (unsigned short*)(hreg + (size_t)PCAP*CDIM*2);   // [18.9, 35.7MB)
    unsigned short* hbuf  = (unsigned short*)hreg;                           // whole region, after te done
    unsigned short* tebuf = (unsigned short*)(ws + take((size_t)PCAP*CDIM*2));
    unsigned short* Wt2   = (unsigned short*)(ws + take((size_t)NE*2*CDIM*MLPD*2));
    unsigned short* Wt3   = Wt2;   // converted after k_mfma_h (mw1 weights dead then)

    k_cvt_x<<<dim3((TTOK*CDIM/4 + 255)/256), dim3(256), 0, stream>>>(x, xb, TTOK*CDIM/4);
    k_cvt_w<<<dim3(CDIM/32, CDIM/32, NE), dim3(256), 0, stream>>>(ex_tw2, Wt1, CDIM, CDIM);
    k_cvt_w<<<dim3(2*CDIM/32, MLPD/32, NE), dim3(256), 0, stream>>>(ex_mw1, Wt2, 2*CDIM, MLPD);
    k_vgelu<<<dim3((PCAP*CDIM)/256), dim3(256), 0, stream>>>(t, ex_tw1, ex_tb1, tok_id, pe, poff, vbuf);
    k_mfma_te<<<dim3(CDIM/128, PCAP/128), dim3(256), 0, stream>>>(vbuf, Wt1, ex_tb2, poff, pe, tebuf);
    k_mfma_h<<<dim3(MLPD/128, PCAP/128), dim3(256), 0, stream>>>(xb, tebuf, Wt2, ex_mb1,
                                                                 poff, pe, tok_id, hbuf);
    k_cvt_w<<<dim3(MLPD/32, CDIM/32, NE), dim3(256), 0, stream>>>(ex_mw2, Wt3, MLPD, CDIM);
    k_mfma_out<<<dim3(CDIM/128, PCAP/128), dim3(256), 0, stream>>>(hbuf, Wt3, ex_mb2,
                                                                   poff, pe, tok_id, pgate, out);
  } else {
    unsigned short* vbuf  = (unsigned short*)(ws + take((size_t)PCAP*MLPD*2)); // union: v then h
    unsigned short* hbuf  = vbuf;
    unsigned short* tebuf = (unsigned short*)(ws + take((size_t)PCAP*CDIM*2));
    k_vgelu<<<dim3((PCAP*CDIM)/256), dim3(256), 0, stream>>>(t, ex_tw1, ex_tb1, tok_id, pe, poff, vbuf);
    k_gemm_te_f<<<dim3(CDIM/64, PCAP/64), dim3(256), 0, stream>>>(vbuf, ex_tw2, ex_tb2, poff, pe, tebuf);
    k_gemm_h_f<<<dim3(MLPD/64, PCAP/64), dim3(256), 0, stream>>>(x, tebuf, ex_mw1, ex_mb1,
                                                                 poff, pe, tok_id, hbuf);
    k_gemm_out_f<<<dim3(CDIM/64, PCAP/64), dim3(256), 0, stream>>>(hbuf, ex_mw2, ex_mb2,
                                                                   poff, pe, tok_id, pgate, out);
  }
  k_loss<<<dim3(1), dim3(64), 0, stream>>>(loadsum, out + (size_t)TTOK*CDIM);
}

// Round 3
// 1160.554 us; speedup vs baseline: 3.0893x; 1.0705x over previous
//
#include <hip/hip_runtime.h>
#include <cmath>

#define TTOK 4096
#define CDIM 1024
#define NE 8
#define MLPD 4096
#define PCAP (2*TTOK + NE*128)   // 9216 padded token-expert pairs max (128-granular)

typedef __attribute__((ext_vector_type(8))) short short8;
typedef __attribute__((ext_vector_type(8))) unsigned short us8;
typedef __attribute__((ext_vector_type(4))) float float4v;

// ---------- helpers ----------
__device__ __forceinline__ float bf2f(unsigned short h){
  return __uint_as_float(((unsigned int)h) << 16);
}
__device__ __forceinline__ unsigned short f2bf(float f){
  unsigned int u = __float_as_uint(f);
  u += 0x7FFFu + ((u >> 16) & 1u);   // RNE
  return (unsigned short)(u >> 16);
}
__device__ __forceinline__ float gelu_exact(float x){
  return 0.5f * x * (1.0f + erff(x * 0.70710678118654752f));
}
// async global->LDS, 16B per lane; LDS dest = wave-uniform base + lane*16
__device__ __forceinline__ void gld16(const void* g, void* l){
  __builtin_amdgcn_global_load_lds((const __attribute__((address_space(1))) void*)g,
                                   (__attribute__((address_space(3))) void*)l, 16, 0, 0);
}
// Swizzled LDS chunk index for tile chunk (row, q): c = row*4 + ((q + (row>>1)) & 3).
// Fragment read offset (in shorts) for absolute tile row m, k-quad qf:
__device__ __forceinline__ int frag_off(int m, int qf){
  return (m*4 + ((qf + (m >> 1)) & 3)) << 3;
}

// ---------- init ----------
__global__ __launch_bounds__(256) void k_zero(float* out, int n, int* counts, float* loadsum){
  int i = blockIdx.x*256 + threadIdx.x;
  if (i < n) out[i] = 0.f;
  if (i < NE){ counts[i] = 0; loadsum[i] = 0.f; }
}

// M2[i][e] = sum_j te_w2[i][j] * gate_w[2C+j][e];  c2[e] = sum_j te_b2[j]*gate_w[2C+j][e]
__global__ __launch_bounds__(256) void k_m2(const float* __restrict__ te_w2,
    const float* __restrict__ te_b2, const float* __restrict__ gate_w,
    float* __restrict__ M2, float* __restrict__ c2){
  int idx = blockIdx.x*256 + threadIdx.x;
  if (idx < CDIM*NE){
    int i = idx >> 3, e = idx & 7;
    float s = 0.f;
    for (int j = 0; j < CDIM; j++)
      s += te_w2[(size_t)i*CDIM + j] * gate_w[(size_t)(2*CDIM + j)*NE + e];
    M2[idx] = s;
  } else if (idx < CDIM*NE + NE){
    int e = idx - CDIM*NE;
    float s = 0.f;
    for (int j = 0; j < CDIM; j++)
      s += te_b2[j] * gate_w[(size_t)(2*CDIM + j)*NE + e];
    c2[e] = s;
  }
}

// ---------- weight conversion: W [E][K][N] fp32 -> Wt [E][N][K] bf16 ----------
// 64x64 tiles: float4 coalesced reads, ushort8 coalesced writes.
__global__ __launch_bounds__(256) void k_cvt_w(const float* __restrict__ W,
    unsigned short* __restrict__ Wt, int K, int N){
  __shared__ unsigned short tile[64*66];   // [k][n], stride 66 shorts
  int kb = blockIdx.x*64, nb = blockIdx.y*64, e = blockIdx.z;
  const float* Wp = W + (size_t)e*K*N + (size_t)kb*N + nb;
  unsigned short* Wo = Wt + (size_t)e*K*N + (size_t)nb*K + kb;
  int tid = threadIdx.x;
  int kr = tid >> 4, nc = (tid & 15)*4;
  #pragma unroll
  for (int i = 0; i < 64; i += 16){
    float4 v = *reinterpret_cast<const float4*>(Wp + (size_t)(kr + i)*N + nc);
    unsigned short* d = &tile[(kr + i)*66 + nc];
    d[0] = f2bf(v.x); d[1] = f2bf(v.y); d[2] = f2bf(v.z); d[3] = f2bf(v.w);
  }
  __syncthreads();
  int nr = tid >> 2, kc = (tid & 3)*16;
  #pragma unroll
  for (int h = 0; h < 2; h++){
    us8 o;
    #pragma unroll
    for (int j = 0; j < 8; j++) o[j] = tile[(kc + h*8 + j)*66 + nr];
    *reinterpret_cast<us8*>(Wo + (size_t)nr*K + kc + h*8) = o;
  }
}

// ---------- gating (also emits x as bf16 when xb != nullptr) ----------
__global__ __launch_bounds__(256) void k_gate(const float* __restrict__ x,
    const float* __restrict__ p, const float* __restrict__ t,
    const float* __restrict__ te_w1, const float* __restrict__ te_b1,
    const float* __restrict__ gate_w, const float* __restrict__ M2,
    const float* __restrict__ c2,
    int* __restrict__ ti, float* __restrict__ tg,
    int* __restrict__ counts, float* __restrict__ loadsum,
    unsigned short* __restrict__ xb){
  int tok = blockIdx.x, tid = threadIdx.x;
  float tv = t[tok];
  float acc[NE];
  #pragma unroll
  for (int e = 0; e < NE; e++) acc[e] = 0.f;
  for (int j = tid; j < CDIM; j += 256){
    float xv = x[(size_t)tok*CDIM + j];
    float pv = p[(size_t)tok*CDIM + j];
    if (xb) xb[(size_t)tok*CDIM + j] = f2bf(xv);
    float vv = gelu_exact(tv*te_w1[j] + te_b1[j]);
    const float* g0 = gate_w + (size_t)j*NE;
    const float* g1 = gate_w + (size_t)(CDIM + j)*NE;
    const float* m2 = M2 + (size_t)j*NE;
    #pragma unroll
    for (int e = 0; e < NE; e++) acc[e] += xv*g0[e] + pv*g1[e] + vv*m2[e];
  }
  __shared__ float red[256][NE];
  #pragma unroll
  for (int e = 0; e < NE; e++) red[tid][e] = acc[e];
  __syncthreads();
  for (int s = 128; s > 0; s >>= 1){
    if (tid < s){
      #pragma unroll
      for (int e = 0; e < NE; e++) red[tid][e] += red[tid+s][e];
    }
    __syncthreads();
  }
  if (tid == 0){
    float lg[NE];
    #pragma unroll
    for (int e = 0; e < NE; e++) lg[e] = red[0][e] + c2[e];
    int i1 = 0; float l1 = lg[0];
    #pragma unroll
    for (int e = 1; e < NE; e++) if (lg[e] > l1){ l1 = lg[e]; i1 = e; }
    int i2 = -1; float l2 = -3.4e38f;
    #pragma unroll
    for (int e = 0; e < NE; e++) if (e != i1 && lg[e] > l2){ l2 = lg[e]; i2 = e; }
    float ex  = expf(l2 - l1);
    float g1v = 1.f/(1.f + ex);
    float g2v = ex/(1.f + ex);
    ti[tok*2]   = i1; ti[tok*2+1] = i2;
    tg[tok*2]   = g1v; tg[tok*2+1] = g2v;
    atomicAdd(&counts[i1], 1);  atomicAdd(&counts[i2], 1);
    atomicAdd(&loadsum[i1], g1v); atomicAdd(&loadsum[i2], g2v);
  }
}

// ---------- dispatch ----------
__global__ __launch_bounds__(256) void k_scan(const int* __restrict__ counts,
    int* __restrict__ poff, int* __restrict__ fillpos,
    int* __restrict__ tok_id, float* __restrict__ pgate, int* __restrict__ pe, int padg){
  __shared__ int so[NE+1];
  __shared__ int sc[NE];
  if (threadIdx.x == 0){
    int o = 0;
    for (int e = 0; e < NE; e++){
      so[e] = o; poff[e] = o; fillpos[e] = o;
      sc[e] = counts[e];
      o += (sc[e] + padg - 1) & ~(padg - 1);
    }
    so[NE] = o; poff[NE] = o;
  }
  __syncthreads();
  for (int e = 0; e < NE; e++){
    int s = so[e] + sc[e], en = so[e+1];
    for (int i = s + (int)threadIdx.x; i < en; i += 256){
      tok_id[i] = 0; pgate[i] = 0.f; pe[i] = e;   // dummy rows: gate 0
    }
  }
}

__global__ __launch_bounds__(256) void k_fill(const int* __restrict__ ti,
    const float* __restrict__ tg, int* __restrict__ fillpos,
    int* __restrict__ tok_id, float* __restrict__ pgate, int* __restrict__ pe,
    int* __restrict__ posmap){
  int tok = blockIdx.x*256 + threadIdx.x;
  if (tok >= TTOK) return;
  #pragma unroll
  for (int k = 0; k < 2; k++){
    int e = ti[tok*2 + k];
    int pos = atomicAdd(&fillpos[e], 1);
    tok_id[pos] = tok;
    pgate[pos]  = tg[tok*2 + k];
    pe[pos]     = e;
    posmap[tok*2 + k] = pos;
  }
}

// v[r][k] = gelu(t_r * tw1[e][k] + tb1[e][k])  (bf16)
__global__ __launch_bounds__(256) void k_vgelu(const float* __restrict__ t,
    const float* __restrict__ tw1, const float* __restrict__ tb1,
    const int* __restrict__ tok_id, const int* __restrict__ pe,
    const int* __restrict__ poff, unsigned short* __restrict__ vbuf){
  int idx = blockIdx.x*256 + threadIdx.x;
  int r = idx >> 10, k = idx & (CDIM - 1);
  if (r >= poff[NE]) return;
  int e = pe[r];
  float tv = t[tok_id[r]];
  float u = tv * tw1[(size_t)e*CDIM + k] + tb1[(size_t)e*CDIM + k];
  vbuf[(size_t)r*CDIM + k] = f2bf(gelu_exact(u));
}

// =========================================================================
// MFMA GEMMs: 128x128 tile, BK=32, 4 waves, 16x16x32 bf16.
// LDS tiles stored as 16B chunks with swizzle c = row*4 + ((q + (row>>1))&3)
// to break the 8-way bank conflict of the naive [row][k] layout while keeping
// global_load_lds's contiguous lane*16B destination (source k-chunk permuted
// within the same 64B row window -> coalescing preserved).
// Frag layouts (measured): A[m=lane&15][k=(lane>>4)*8+j];
// B[n=lane&15][k=(lane>>4)*8+j]; C/D col=lane&15, row=(lane>>4)*4+reg.
// =========================================================================

// GEMM1: te = v @ tw2[e] + tb2[e]   (K=1024, N=1024)
__global__ __launch_bounds__(256,2) void k_mfma_te(
    const unsigned short* __restrict__ vbuf,
    const unsigned short* __restrict__ Wt1, const float* __restrict__ tb2,
    const int* __restrict__ poff, const int* __restrict__ pe,
    unsigned short* __restrict__ tebuf){
  __shared__ unsigned short As[128*32];
  __shared__ unsigned short Bs[128*32];
  int r0 = blockIdx.y * 128;
  if (r0 >= poff[NE]) return;
  int e = pe[r0];
  int n0 = blockIdx.x * 128;
  int tid = threadIdx.x, lane = tid & 63, w = tid >> 6;
  const unsigned short* Bp = Wt1 + (size_t)e*CDIM*CDIM;   // [N][K]
  int mb = (w&1)*64, nb = (w>>1)*64;
  float4v acc[4][4];
  #pragma unroll
  for (int i=0;i<4;i++)
    #pragma unroll
    for (int j=0;j<4;j++) acc[i][j] = (float4v){0.f,0.f,0.f,0.f};
  int rowA = w*32 + (lane>>2);
  int ck = (((lane & 3) - ((lane >> 3) & 3)) & 3) * 8;   // swizzled source k-chunk
  int r15 = lane & 15, qf = lane >> 4;
  for (int k0 = 0; k0 < CDIM; k0 += 32){
    __syncthreads();
    unsigned short* lA = As + (w*32)*32;
    unsigned short* lB = Bs + (w*32)*32;
    gld16(vbuf + (size_t)(r0+rowA)*CDIM + k0 + ck, lA);
    gld16(vbuf + (size_t)(r0+rowA+16)*CDIM + k0 + ck, lA + 16*32);
    gld16(Bp + (size_t)(n0+rowA)*CDIM + k0 + ck, lB);
    gld16(Bp + (size_t)(n0+rowA+16)*CDIM + k0 + ck, lB + 16*32);
    __syncthreads();
    short8 a[4], b[4];
    #pragma unroll
    for (int mi=0;mi<4;mi++) a[mi] = *(const short8*)(As + frag_off(mb+mi*16+r15, qf));
    #pragma unroll
    for (int ni=0;ni<4;ni++) b[ni] = *(const short8*)(Bs + frag_off(nb+ni*16+r15, qf));
    #pragma unroll
    for (int mi=0;mi<4;mi++)
      #pragma unroll
      for (int ni=0;ni<4;ni++)
        acc[mi][ni] = __builtin_amdgcn_mfma_f32_16x16x32_bf16(a[mi], b[ni], acc[mi][ni], 0, 0, 0);
  }
  int col = lane & 15, rq = (lane>>4)*4;
  const float* bias = tb2 + (size_t)e*CDIM + n0;
  #pragma unroll
  for (int mi=0;mi<4;mi++)
    #pragma unroll
    for (int ni=0;ni<4;ni++){
      int n = nb + ni*16 + col;
      #pragma unroll
      for (int rg=0;rg<4;rg++){
        int r = r0 + mb + mi*16 + rq + rg;
        tebuf[(size_t)r*CDIM + n0 + n] = f2bf(acc[mi][ni][rg] + bias[n]);
      }
    }
}

// GEMM2: h = gelu([x|te] @ mw1[e] + mb1[e])   (K=2048, N=4096)
__global__ __launch_bounds__(256,2) void k_mfma_h(
    const unsigned short* __restrict__ xb, const unsigned short* __restrict__ tebuf,
    const unsigned short* __restrict__ Wt2, const float* __restrict__ mb1,
    const int* __restrict__ poff, const int* __restrict__ pe,
    const int* __restrict__ tok_id, unsigned short* __restrict__ hbuf){
  __shared__ unsigned short As[128*32];
  __shared__ unsigned short Bs[128*32];
  __shared__ int toks[128];
  int r0 = blockIdx.y * 128;
  if (r0 >= poff[NE]) return;
  int e = pe[r0];
  int n0 = blockIdx.x * 128;
  int tid = threadIdx.x, lane = tid & 63, w = tid >> 6;
  if (tid < 128) toks[tid] = tok_id[r0 + tid];
  const unsigned short* Bp = Wt2 + (size_t)e*(2*CDIM)*MLPD;   // [N][K]
  int mb = (w&1)*64, nb = (w>>1)*64;
  float4v acc[4][4];
  #pragma unroll
  for (int i=0;i<4;i++)
    #pragma unroll
    for (int j=0;j<4;j++) acc[i][j] = (float4v){0.f,0.f,0.f,0.f};
  int rowA = w*32 + (lane>>2);
  int ck = (((lane & 3) - ((lane >> 3) & 3)) & 3) * 8;
  int r15 = lane & 15, qf = lane >> 4;
  __syncthreads();
  for (int k0 = 0; k0 < 2*CDIM; k0 += 32){
    __syncthreads();
    unsigned short* lA = As + (w*32)*32;
    unsigned short* lB = Bs + (w*32)*32;
    if (k0 < CDIM){
      int tok0 = toks[rowA], tok1 = toks[rowA+16];
      gld16(xb + (size_t)tok0*CDIM + k0 + ck, lA);
      gld16(xb + (size_t)tok1*CDIM + k0 + ck, lA + 16*32);
    } else {
      gld16(tebuf + (size_t)(r0+rowA)*CDIM + (k0-CDIM) + ck, lA);
      gld16(tebuf + (size_t)(r0+rowA+16)*CDIM + (k0-CDIM) + ck, lA + 16*32);
    }
    gld16(Bp + (size_t)(n0+rowA)*(2*CDIM) + k0 + ck, lB);
    gld16(Bp + (size_t)(n0+rowA+16)*(2*CDIM) + k0 + ck, lB + 16*32);
    __syncthreads();
    short8 a[4], b[4];
    #pragma unroll
    for (int mi=0;mi<4;mi++) a[mi] = *(const short8*)(As + frag_off(mb+mi*16+r15, qf));
    #pragma unroll
    for (int ni=0;ni<4;ni++) b[ni] = *(const short8*)(Bs + frag_off(nb+ni*16+r15, qf));
    #pragma unroll
    for (int mi=0;mi<4;mi++)
      #pragma unroll
      for (int ni=0;ni<4;ni++)
        acc[mi][ni] = __builtin_amdgcn_mfma_f32_16x16x32_bf16(a[mi], b[ni], acc[mi][ni], 0, 0, 0);
  }
  int col = lane & 15, rq = (lane>>4)*4;
  const float* bias = mb1 + (size_t)e*MLPD + n0;
  #pragma unroll
  for (int mi=0;mi<4;mi++)
    #pragma unroll
    for (int ni=0;ni<4;ni++){
      int n = nb + ni*16 + col;
      #pragma unroll
      for (int rg=0;rg<4;rg++){
        int r = r0 + mb + mi*16 + rq + rg;
        hbuf[(size_t)r*MLPD + n0 + n] = f2bf(gelu_exact(acc[mi][ni][rg] + bias[n]));
      }
    }
}

// GEMM3: obuf[r] = h[r] @ mw2[e] + mb2[e]   (K=4096, N=1024) — no atomics
__global__ __launch_bounds__(256,2) void k_mfma_out(
    const unsigned short* __restrict__ hbuf,
    const unsigned short* __restrict__ Wt3, const float* __restrict__ mb2,
    const int* __restrict__ poff, const int* __restrict__ pe,
    float* __restrict__ obuf){
  __shared__ unsigned short As[128*32];
  __shared__ unsigned short Bs[128*32];
  int r0 = blockIdx.y * 128;
  if (r0 >= poff[NE]) return;
  int e = pe[r0];
  int n0 = blockIdx.x * 128;
  int tid = threadIdx.x, lane = tid & 63, w = tid >> 6;
  const unsigned short* Bp = Wt3 + (size_t)e*MLPD*CDIM;   // [N][K]
  int mb = (w&1)*64, nb = (w>>1)*64;
  float4v acc[4][4];
  #pragma unroll
  for (int i=0;i<4;i++)
    #pragma unroll
    for (int j=0;j<4;j++) acc[i][j] = (float4v){0.f,0.f,0.f,0.f};
  int rowA = w*32 + (lane>>2);
  int ck = (((lane & 3) - ((lane >> 3) & 3)) & 3) * 8;
  int r15 = lane & 15, qf = lane >> 4;
  for (int k0 = 0; k0 < MLPD; k0 += 32){
    __syncthreads();
    unsigned short* lA = As + (w*32)*32;
    unsigned short* lB = Bs + (w*32)*32;
    gld16(hbuf + (size_t)(r0+rowA)*MLPD + k0 + ck, lA);
    gld16(hbuf + (size_t)(r0+rowA+16)*MLPD + k0 + ck, lA + 16*32);
    gld16(Bp + (size_t)(n0+rowA)*MLPD + k0 + ck, lB);
    gld16(Bp + (size_t)(n0+rowA+16)*MLPD + k0 + ck, lB + 16*32);
    __syncthreads();
    short8 a[4], b[4];
    #pragma unroll
    for (int mi=0;mi<4;mi++) a[mi] = *(const short8*)(As + frag_off(mb+mi*16+r15, qf));
    #pragma unroll
    for (int ni=0;ni<4;ni++) b[ni] = *(const short8*)(Bs + frag_off(nb+ni*16+r15, qf));
    #pragma unroll
    for (int mi=0;mi<4;mi++)
      #pragma unroll
      for (int ni=0;ni<4;ni++)
        acc[mi][ni] = __builtin_amdgcn_mfma_f32_16x16x32_bf16(a[mi], b[ni], acc[mi][ni], 0, 0, 0);
  }
  int col = lane & 15, rq = (lane>>4)*4;
  const float* bias = mb2 + (size_t)e*CDIM + n0;
  #pragma unroll
  for (int mi=0;mi<4;mi++)
    #pragma unroll
    for (int ni=0;ni<4;ni++){
      int n = nb + ni*16 + col;
      #pragma unroll
      for (int rg=0;rg<4;rg++){
        int r = r0 + mb + mi*16 + rq + rg;
        obuf[(size_t)r*CDIM + n0 + n] = acc[mi][ni][rg] + bias[n];
      }
    }
}

// combine: out[tok] = g1*obuf[p1] + g2*obuf[p2]
__global__ __launch_bounds__(256) void k_combine(const float* __restrict__ obuf,
    const int* __restrict__ posmap, const float* __restrict__ tg,
    float* __restrict__ out){
  int idx = blockIdx.x*256 + threadIdx.x;    // over TTOK*CDIM/4
  int tok = idx >> 8, n4 = (idx & 255)*4;
  int p1 = posmap[tok*2], p2 = posmap[tok*2+1];
  float g1 = tg[tok*2], g2 = tg[tok*2+1];
  float4 a = *reinterpret_cast<const float4*>(obuf + (size_t)p1*CDIM + n4);
  float4 b = *reinterpret_cast<const float4*>(obuf + (size_t)p2*CDIM + n4);
  float4 o;
  o.x = g1*a.x + g2*b.x; o.y = g1*a.y + g2*b.y;
  o.z = g1*a.z + g2*b.z; o.w = g1*a.w + g2*b.w;
  *reinterpret_cast<float4*>(out + (size_t)tok*CDIM + n4) = o;
}

// =========================================================================
// Fallback fp32 path (64-row tiles) — used only if ws too small
// =========================================================================
__global__ __launch_bounds__(256) void k_gemm_te_f(
    const unsigned short* __restrict__ vbuf,
    const float* __restrict__ tw2, const float* __restrict__ tb2,
    const int* __restrict__ poff, const int* __restrict__ pe,
    unsigned short* __restrict__ tebuf){
  int r0 = blockIdx.y * 64;
  if (r0 >= poff[NE]) return;
  int e = pe[r0];
  int n0 = blockIdx.x * 64;
  const float* Bp = tw2 + (size_t)e*CDIM*CDIM;
  __shared__ float As[16][68];
  __shared__ float Bs[16][68];
  int tid = threadIdx.x;
  int tx = tid & 15, ty = tid >> 4;
  int lm = tid >> 2, lk = (tid & 3)*4;
  int bk = tid >> 4, bn = (tid & 15)*4;
  float acc[4][4] = {{0.f}};
  for (int k0 = 0; k0 < CDIM; k0 += 16){
    ushort4 av = *reinterpret_cast<const ushort4*>(vbuf + (size_t)(r0+lm)*CDIM + k0 + lk);
    float4  bv = *reinterpret_cast<const float4*>(Bp + (size_t)(k0+bk)*CDIM + n0 + bn);
    __syncthreads();
    As[lk+0][lm] = bf2f(av.x); As[lk+1][lm] = bf2f(av.y);
    As[lk+2][lm] = bf2f(av.z); As[lk+3][lm] = bf2f(av.w);
    *reinterpret_cast<float4*>(&Bs[bk][bn]) = bv;
    __syncthreads();
    #pragma unroll
    for (int k = 0; k < 16; k++){
      float4 a = *reinterpret_cast<const float4*>(&As[k][ty*4]);
      float4 b = *reinterpret_cast<const float4*>(&Bs[k][tx*4]);
      float am[4] = {a.x,a.y,a.z,a.w}, bn4[4] = {b.x,b.y,b.z,b.w};
      #pragma unroll
      for (int i = 0; i < 4; i++)
        #pragma unroll
        for (int j = 0; j < 4; j++) acc[i][j] += am[i]*bn4[j];
    }
  }
  #pragma unroll
  for (int i = 0; i < 4; i++){
    int r = r0 + ty*4 + i;
    #pragma unroll
    for (int j = 0; j < 4; j++){
      int n = n0 + tx*4 + j;
      tebuf[(size_t)r*CDIM + n] = f2bf(acc[i][j] + tb2[(size_t)e*CDIM + n]);
    }
  }
}

__global__ __launch_bounds__(256) void k_gemm_h_f(
    const float* __restrict__ x, const unsigned short* __restrict__ tebuf,
    const float* __restrict__ mw1, const float* __restrict__ mb1,
    const int* __restrict__ poff, const int* __restrict__ pe,
    const int* __restrict__ tok_id, unsigned short* __restrict__ hbuf){
  int r0 = blockIdx.y * 64;
  if (r0 >= poff[NE]) return;
  int e = pe[r0];
  int n0 = blockIdx.x * 64;
  const float* Bp = mw1 + (size_t)e*(2*CDIM)*MLPD;
  __shared__ float As[16][68];
  __shared__ float Bs[16][68];
  __shared__ int toks[64];
  int tid = threadIdx.x;
  if (tid < 64) toks[tid] = tok_id[r0 + tid];
  int tx = tid & 15, ty = tid >> 4;
  int lm = tid >> 2, lk = (tid & 3)*4;
  int bk = tid >> 4, bn = (tid & 15)*4;
  float acc[4][4] = {{0.f}};
  __syncthreads();
  for (int k0 = 0; k0 < 2*CDIM; k0 += 16){
    float4 af;
    if (k0 < CDIM){
      af = *reinterpret_cast<const float4*>(x + (size_t)toks[lm]*CDIM + k0 + lk);
    } else {
      ushort4 av = *reinterpret_cast<const ushort4*>(tebuf + (size_t)(r0+lm)*CDIM + (k0 - CDIM) + lk);
      af.x = bf2f(av.x); af.y = bf2f(av.y); af.z = bf2f(av.z); af.w = bf2f(av.w);
    }
    float4 bv = *reinterpret_cast<const float4*>(Bp + (size_t)(k0+bk)*MLPD + n0 + bn);
    __syncthreads();
    As[lk+0][lm] = af.x; As[lk+1][lm] = af.y;
    As[lk+2][lm] = af.z; As[lk+3][lm] = af.w;
    *reinterpret_cast<float4*>(&Bs[bk][bn]) = bv;
    __syncthreads();
    #pragma unroll
    for (int k = 0; k < 16; k++){
      float4 a = *reinterpret_cast<const float4*>(&As[k][ty*4]);
      float4 b = *reinterpret_cast<const float4*>(&Bs[k][tx*4]);
      float am[4] = {a.x,a.y,a.z,a.w}, bn4[4] = {b.x,b.y,b.z,b.w};
      #pragma unroll
      for (int i = 0; i < 4; i++)
        #pragma unroll
        for (int j = 0; j < 4; j++) acc[i][j] += am[i]*bn4[j];
    }
  }
  #pragma unroll
  for (int i = 0; i < 4; i++){
    int r = r0 + ty*4 + i;
    #pragma unroll
    for (int j = 0; j < 4; j++){
      int n = n0 + tx*4 + j;
      hbuf[(size_t)r*MLPD + n] = f2bf(gelu_exact(acc[i][j] + mb1[(size_t)e*MLPD + n]));
    }
  }
}

__global__ __launch_bounds__(256) void k_gemm_out_f(
    const unsigned short* __restrict__ hbuf,
    const float* __restrict__ mw2, const float* __restrict__ mb2,
    const int* __restrict__ poff, const int* __restrict__ pe,
    const int* __restrict__ tok_id, const float* __restrict__ pgate,
    float* __restrict__ out){
  int r0 = blockIdx.y * 64;
  if (r0 >= poff[NE]) return;
  int e = pe[r0];
  int n0 = blockIdx.x * 64;
  const float* Bp = mw2 + (size_t)e*MLPD*CDIM;
  __shared__ float As[16][68];
  __shared__ float Bs[16][68];
  __shared__ int   toks[64];
  __shared__ float gts[64];
  int tid = threadIdx.x;
  if (tid < 64){ toks[tid] = tok_id[r0 + tid]; gts[tid] = pgate[r0 + tid]; }
  int tx = tid & 15, ty = tid >> 4;
  int lm = tid >> 2, lk = (tid & 3)*4;
  int bk = tid >> 4, bn = (tid & 15)*4;
  float acc[4][4] = {{0.f}};
  __syncthreads();
  for (int k0 = 0; k0 < MLPD; k0 += 16){
    ushort4 av = *reinterpret_cast<const ushort4*>(hbuf + (size_t)(r0+lm)*MLPD + k0 + lk);
    float4  bv = *reinterpret_cast<const float4*>(Bp + (size_t)(k0+bk)*CDIM + n0 + bn);
    __syncthreads();
    As[lk+0][lm] = bf2f(av.x); As[lk+1][lm] = bf2f(av.y);
    As[lk+2][lm] = bf2f(av.z); As[lk+3][lm] = bf2f(av.w);
    *reinterpret_cast<float4*>(&Bs[bk][bn]) = bv;
    __syncthreads();
    #pragma unroll
    for (int k = 0; k < 16; k++){
      float4 a = *reinterpret_cast<const float4*>(&As[k][ty*4]);
      float4 b = *reinterpret_cast<const float4*>(&Bs[k][tx*4]);
      float am[4] = {a.x,a.y,a.z,a.w}, bn4[4] = {b.x,b.y,b.z,b.w};
      #pragma unroll
      for (int i = 0; i < 4; i++)
        #pragma unroll
        for (int j = 0; j < 4; j++) acc[i][j] += am[i]*bn4[j];
    }
  }
  #pragma unroll
  for (int i = 0; i < 4; i++){
    int rl = ty*4 + i;
    int tok = toks[rl];
    float g = gts[rl];
    #pragma unroll
    for (int j = 0; j < 4; j++){
      int n = n0 + tx*4 + j;
      float val = acc[i][j] + mb2[(size_t)e*CDIM + n];
      atomicAdd(&out[(size_t)tok*CDIM + n], g*val);
    }
  }
}

// ---------- loss ----------
__global__ void k_loss(const float* __restrict__ loadsum, float* __restrict__ outp){
  if (threadIdx.x == 0 && blockIdx.x == 0){
    float m = 0.f;
    for (int e = 0; e < NE; e++) m += loadsum[e];
    m *= (1.f/NE);
    float v = 0.f;
    for (int e = 0; e < NE; e++){ float d = loadsum[e] - m; v += d*d; }
    v *= (1.f/(NE-1));
    float bal = v / (m*m + 1e-10f);
    outp[0] = 2.f * bal;
  }
}

extern "C" void kernel_launch(void* const* d_in, const int* in_sizes, int n_in,
                              void* d_out, int out_size, void* d_ws, size_t ws_size,
                              hipStream_t stream){
  const float* x      = (const float*)d_in[0];
  const float* p      = (const float*)d_in[1];
  const float* t      = (const float*)d_in[2];
  const float* te_w1  = (const float*)d_in[3];
  const float* te_b1  = (const float*)d_in[4];
  const float* te_w2  = (const float*)d_in[5];
  const float* te_b2  = (const float*)d_in[6];
  const float* gate_w = (const float*)d_in[7];
  const float* ex_tw1 = (const float*)d_in[8];
  const float* ex_tb1 = (const float*)d_in[9];
  const float* ex_tw2 = (const float*)d_in[10];
  const float* ex_tb2 = (const float*)d_in[11];
  const float* ex_mw1 = (const float*)d_in[12];
  const float* ex_mb1 = (const float*)d_in[13];
  const float* ex_mw2 = (const float*)d_in[14];
  const float* ex_mb2 = (const float*)d_in[15];
  float* out = (float*)d_out;

  char* ws = (char*)d_ws;
  size_t off = 0;
  auto take = [&](size_t b){ size_t r = off; off = (off + b + 255) & ~(size_t)255; return r; };
  int*   counts  = (int*)  (ws + take(NE*sizeof(int)));
  int*   fillpos = (int*)  (ws + take(NE*sizeof(int)));
  int*   poff    = (int*)  (ws + take((NE+1)*sizeof(int)));
  float* loadsum = (float*)(ws + take(NE*sizeof(float)));
  float* M2      = (float*)(ws + take((size_t)CDIM*NE*sizeof(float)));
  float* c2      = (float*)(ws + take(NE*sizeof(float)));
  int*   ti      = (int*)  (ws + take((size_t)TTOK*2*sizeof(int)));
  float* tg      = (float*)(ws + take((size_t)TTOK*2*sizeof(float)));
  int*   posmap  = (int*)  (ws + take((size_t)TTOK*2*sizeof(int)));
  int*   tok_id  = (int*)  (ws + take((size_t)PCAP*sizeof(int)));
  float* pgate   = (float*)(ws + take((size_t)PCAP*sizeof(float)));
  int*   pe      = (int*)  (ws + take((size_t)PCAP*sizeof(int)));

  // MFMA path: xb + hbuf-region(vbuf+Wt1) + tebuf + Wt2-region(Wt3+obuf in tail)
  size_t need_mfma = off
      + ((size_t)TTOK*CDIM*2 + 256)          // xb
      + ((size_t)PCAP*MLPD*2 + 256)          // hbuf region (hosts vbuf + Wt1)
      + ((size_t)PCAP*CDIM*2 + 256)          // tebuf
      + ((size_t)NE*2*CDIM*MLPD*2 + 256);    // Wt2 region (hosts Wt3 + obuf later)
  bool use_mfma = ws_size >= need_mfma;
  int padg = use_mfma ? 128 : 64;

  int nOut = TTOK*CDIM + 1;
  k_zero<<<dim3((nOut + 255)/256), dim3(256), 0, stream>>>(out, nOut, counts, loadsum);
  k_m2<<<dim3((CDIM*NE + NE + 255)/256), dim3(256), 0, stream>>>(te_w2, te_b2, gate_w, M2, c2);

  if (use_mfma){
    unsigned short* xb    = (unsigned short*)(ws + take((size_t)TTOK*CDIM*2));
    char*           hreg  = ws + take((size_t)PCAP*MLPD*2);
    unsigned short* vbuf  = (unsigned short*)hreg;
    unsigned short* Wt1   = (unsigned short*)(hreg + (size_t)PCAP*CDIM*2);
    unsigned short* hbuf  = (unsigned short*)hreg;   // whole region, after te done
    unsigned short* tebuf = (unsigned short*)(ws + take((size_t)PCAP*CDIM*2));
    unsigned short* Wt2   = (unsigned short*)(ws + take((size_t)NE*2*CDIM*MLPD*2));
    unsigned short* Wt3   = Wt2;                                          // after k_mfma_h
    float*          obuf  = (float*)(Wt2 + (size_t)NE*MLPD*CDIM);         // dead Wt2 tail

    k_gate<<<dim3(TTOK), dim3(256), 0, stream>>>(x, p, t, te_w1, te_b1, gate_w, M2, c2,
                                                 ti, tg, counts, loadsum, xb);
    k_scan<<<dim3(1), dim3(256), 0, stream>>>(counts, poff, fillpos, tok_id, pgate, pe, padg);
    k_fill<<<dim3((TTOK + 255)/256), dim3(256), 0, stream>>>(ti, tg, fillpos, tok_id, pgate, pe, posmap);
    k_cvt_w<<<dim3(CDIM/64, CDIM/64, NE), dim3(256), 0, stream>>>(ex_tw2, Wt1, CDIM, CDIM);
    k_cvt_w<<<dim3(2*CDIM/64, MLPD/64, NE), dim3(256), 0, stream>>>(ex_mw1, Wt2, 2*CDIM, MLPD);
    k_vgelu<<<dim3((PCAP*CDIM)/256), dim3(256), 0, stream>>>(t, ex_tw1, ex_tb1, tok_id, pe, poff, vbuf);
    k_mfma_te<<<dim3(CDIM/128, PCAP/128), dim3(256), 0, stream>>>(vbuf, Wt1, ex_tb2, poff, pe, tebuf);
    k_mfma_h<<<dim3(MLPD/128, PCAP/128), dim3(256), 0, stream>>>(xb, tebuf, Wt2, ex_mb1,
                                                                 poff, pe, tok_id, hbuf);
    k_cvt_w<<<dim3(MLPD/64, CDIM/64, NE), dim3(256), 0, stream>>>(ex_mw2, Wt3, MLPD, CDIM);
    k_mfma_out<<<dim3(CDIM/128, PCAP/128), dim3(256), 0, stream>>>(hbuf, Wt3, ex_mb2,
                                                                   poff, pe, obuf);
    k_combine<<<dim3((TTOK*CDIM/4)/256), dim3(256), 0, stream>>>(obuf, posmap, tg, out);
  } else {
    unsigned short* vbuf  = (unsigned short*)(ws + take((size_t)PCAP*MLPD*2));
    unsigned short* hbuf  = vbuf;
    unsigned short* tebuf = (unsigned short*)(ws + take((size_t)PCAP*CDIM*2));
    k_gate<<<dim3(TTOK), dim3(256), 0, stream>>>(x, p, t, te_w1, te_b1, gate_w, M2, c2,
                                                 ti, tg, counts, loadsum, (unsigned short*)nullptr);
    k_scan<<<dim3(1), dim3(256), 0, stream>>>(counts, poff, fillpos, tok_id, pgate, pe, padg);
    k_fill<<<dim3((TTOK + 255)/256), dim3(256), 0, stream>>>(ti, tg, fillpos, tok_id, pgate, pe, posmap);
    k_vgelu<<<dim3((PCAP*CDIM)/256), dim3(256), 0, stream>>>(t, ex_tw1, ex_tb1, tok_id, pe, poff, vbuf);
    k_gemm_te_f<<<dim3(CDIM/64, PCAP/64), dim3(256), 0, stream>>>(vbuf, ex_tw2, ex_tb2, poff, pe, tebuf);
    k_gemm_h_f<<<dim3(MLPD/64, PCAP/64), dim3(256), 0, stream>>>(x, tebuf, ex_mw1, ex_mb1,
                                                                 poff, pe, tok_id, hbuf);
    k_gemm_out_f<<<dim3(CDIM/64, PCAP/64), dim3(256), 0, stream>>>(hbuf, ex_mw2, ex_mb2,
                                                                   poff, pe, tok_id, pgate, out);
  }
  k_loss<<<dim3(1), dim3(64), 0, stream>>>(loadsum, out + (size_t)TTOK*CDIM);
}